// Round 6
// baseline (125.063 us; speedup 1.0000x reference)
//
#include <hip/hip_runtime.h>

// ---- types ----
typedef __bf16 bf8_t  __attribute__((ext_vector_type(8)));   // 8 x bf16 = 4 VGPR (MFMA A/B frag)
typedef float  f4_t   __attribute__((ext_vector_type(4)));   // MFMA C/D frag
typedef unsigned short us4_t __attribute__((ext_vector_type(4)));

#define N_ROWS 4096
#define D_K    1024
#define TEMP_INV 20.0f   // 1 / 0.05  (folded into x-normalization)

// fp32 -> bf16, round-to-nearest-even (no NaN in this problem)
__device__ __forceinline__ unsigned short f2bf(float f) {
    unsigned int u = __builtin_bit_cast(unsigned int, f);
    u += 0x7fffu + ((u >> 16) & 1u);
    return (unsigned short)(u >> 16);
}

// async global->LDS, 16B per lane. LDS dest must be wave-uniform base + lane*16.
__device__ __forceinline__ void gl_lds16(const __bf16* g, __bf16* l) {
    __builtin_amdgcn_global_load_lds(
        (const __attribute__((address_space(1))) unsigned int*)g,
        (__attribute__((address_space(3))) unsigned int*)l,
        16, 0, 0);
}

// ---------------- fused row normalize for both inputs: v / max(||v||, eps), fp32 -> bf16 ----
// (unchanged, verified; ~7.6 us, at memory roofline for 48 MB)
__global__ __launch_bounds__(256) void norm_rows_kernel(
    const float* __restrict__ x, const float* __restrict__ y,
    unsigned short* __restrict__ xb, unsigned short* __restrict__ yb)
{
    const int b   = blockIdx.x;
    const int row = b & (N_ROWS - 1);
    const bool isx = (b < N_ROWS);
    const float* in     = isx ? x  : y;
    unsigned short* out = isx ? xb : yb;
    const float post    = isx ? TEMP_INV : 1.0f;
    const int t = threadIdx.x;
    const float4* ip = (const float4*)(in + (size_t)row * D_K);
    float4 v = ip[t];
    float ss = v.x*v.x + v.y*v.y + v.z*v.z + v.w*v.w;
    #pragma unroll
    for (int off = 32; off > 0; off >>= 1)
        ss += __shfl_down(ss, off, 64);
    __shared__ float red[4];
    if ((t & 63) == 0) red[t >> 6] = ss;
    __syncthreads();
    float tot   = red[0] + red[1] + red[2] + red[3];
    float scale = post / fmaxf(sqrtf(tot), 1e-8f);
    us4_t o;
    o.x = f2bf(v.x * scale);
    o.y = f2bf(v.y * scale);
    o.z = f2bf(v.z * scale);
    o.w = f2bf(v.w * scale);
    *(us4_t*)(out + (size_t)row * D_K + t * 4) = o;
}

// ---------------- C = A . B^T  ----------------------------------------------------------
// 256x256 tile, BK=64, 512 threads = 8 waves (2 M-halves x 4 N-quarters), per-wave 128x64 C.
//
// R6: WAR-free register rotation. R5 post-mortem: barriers don't drain the matrix pipe
// (a wave crosses after ISSUING MFMAs), so reads CAN drain under the ~620cyc/SIMD matrix
// backlog — unless the read's destination register is an operand of in-flight MFMAs (WAR):
// the LDS return then stalls until those MFMAs consume it, and in-order LDS write-back
// clogs the whole read queue. R5 had exactly one hard WAR: RD b0(NXT) immediately after
// Q10 (whose operand IS b0) — ~600cyc/tile serializer. Fix: B(q0) gets TWO register sets
// alternating by tile parity (bU0/bU1); the next-tile B(q0) prefetch moves BEFORE Q10 and
// targets the set that has been idle a full tile -> zero WAR. All reads now have >=1 full
// cluster between last consumption and re-read; no post-cluster reads remain.
//
// Steady-state tile (entry: 12 reads {afX(q0), bUse(q0)} outstanding, issued pre-C4 of
// the previous tile; they drained under prev C4):
//   STAGE 8 -> buf[nxt]                         (tile t+1; vm only)
//   lgkm(0)                                     <- entry reads (already drained)
//   RD bV(cur,q1) [4] ; C1 = Q00(afX,bUse)      bV drains under C1
//   lgkm(0) ; RD afY(cur,q1) [8] ; C2 = Q01(afX,bV)   afY drains under C2; afX dead
//   lgkm(0) ; C3 = Q11(afY,bV)                  bV dead
//   vmcnt(0) ; barrier                          <- publish buf[nxt]; stages ~1900cyc old
//   RD afX'(nxt,q0) [8] + RD bUnxt'(nxt,q0) [4] ; C4 = Q10(afY,bUse)
//     (afX': last use C2, gap C3 ~620cyc OK; bUnxt': idle since prev-parity tile OK)
// One barrier/tile. Race-freedom: every read of buf[cur] is lgkm-fenced before the
// mid-tile barrier; the overwrite of buf[cur] is issued only after that barrier (t+1 P1).
//
// Regs: afX 32 + afY 32 + bV 16 + bU0 16 + bU1 16 = 112 frag VGPR + 128 acc = 240 (<256).
//
// LDS swizzle: slot (row, g) holds global 8-elem k-group g ^ (row&7); applied on the
// GLOBAL source address during staging. Fragment read start group = (quad+4*kk)^(l15&7)
// -> measured ZERO SQ_LDS_BANK_CONFLICT (R1-R5). Keep 16x16x32 MFMA (32x32 regressed).
// Grid: plain 2-D (XCD swizzle measured null in R4); plain launch (coop was -24us, R2).
__global__ __launch_bounds__(512, 2) void cosim_gemm256_kernel(
    const unsigned short* __restrict__ Aus,
    const unsigned short* __restrict__ Bus,
    float* __restrict__ C)
{
    const __bf16* A = (const __bf16*)Aus;
    const __bf16* B = (const __bf16*)Bus;

    __shared__ __align__(16) __bf16 As[2][256 * 64];   // 64 KB
    __shared__ __align__(16) __bf16 Bs[2][256 * 64];   // 64 KB

    const int t    = threadIdx.x;
    const int lane = t & 63;
    const int wid  = t >> 6;       // 0..7
    const int wm   = wid >> 2;     // 0..1   M half
    const int wn   = wid & 3;      // 0..3   N quarter
    const int bm   = blockIdx.x;
    const int bn   = blockIdx.y;
    const int l15  = lane & 15;
    const int quad = lane >> 4;

    // ---- staging constants (stager == reader partition) ----
    const int slA0 = wn * 64 + lane;          // 0..255  virtual lane over the wm-group
    const int slA1 = slA0 + 256;
    const int rA0 = slA0 >> 3, rA1 = slA1 >> 3;
    const int gA0 = (slA0 & 7) ^ (rA0 & 7);   // swizzled global k-group
    const int gA1 = (slA1 & 7) ^ (rA1 & 7);
    const unsigned gaOff0 = (unsigned)(bm * 256 + wm * 128 + rA0) * D_K + gA0 * 8;
    const unsigned gaOff1 = (unsigned)(bm * 256 + wm * 128 + rA1) * D_K + gA1 * 8;
    const int laOff0 = wm * 8192 + slA0 * 8;  // elems; + qm*4096
    const int laOff1 = wm * 8192 + slA1 * 8;
    const int slB0 = wm * 64 + lane;          // 0..127  virtual lane over the wn-group
    const int slB1 = slB0 + 128;
    const int rB0 = slB0 >> 3, rB1 = slB1 >> 3;
    const int gB0 = (slB0 & 7) ^ (rB0 & 7);
    const int gB1 = (slB1 & 7) ^ (rB1 & 7);
    const unsigned gbOff0 = (unsigned)(bn * 256 + wn * 64 + rB0) * D_K + gB0 * 8;
    const unsigned gbOff1 = (unsigned)(bn * 256 + wn * 64 + rB1) * D_K + gB1 * 8;
    const int lbOff0 = wn * 4096 + slB0 * 8;  // elems; + qn*2048
    const int lbOff1 = wn * 4096 + slB1 * 8;

#define STAGE_ALL(buf, kelem) do { \
    gl_lds16(A + gaOff0 + (kelem),         &As[buf][laOff0]); \
    gl_lds16(A + gaOff1 + (kelem),         &As[buf][laOff1]); \
    gl_lds16(B + gbOff0 + (kelem),         &Bs[buf][lbOff0]); \
    gl_lds16(B + gbOff1 + (kelem),         &Bs[buf][lbOff1]); \
    gl_lds16(B + gbOff0 + 32768 + (kelem), &Bs[buf][lbOff0 + 2048]); \
    gl_lds16(B + gbOff1 + 32768 + (kelem), &Bs[buf][lbOff1 + 2048]); \
    gl_lds16(A + gaOff0 + 65536 + (kelem), &As[buf][laOff0 + 4096]); \
    gl_lds16(A + gaOff1 + 65536 + (kelem), &As[buf][laOff1 + 4096]); } while (0)

    // ---- fragment read constants ----
    const int g0 = quad ^ (l15 & 7);          // kk=0 swizzled group
    const int g1 = (quad + 4) ^ (l15 & 7);    // kk=1
    const int aRd = (wm * 128 + l15) * 64;    // + qm*4096 + mi*1024 + g*8
    const int bRd = (wn * 64 + l15) * 64;     // + qn*2048 + ni*1024 + g*8

#define RD_AF(SET, BUF, qm) do { _Pragma("unroll") \
    for (int mi = 0; mi < 4; mi++) { \
        SET[mi][0] = *(const bf8_t*)(&As[BUF][aRd + (qm) * 4096 + mi * 1024 + g0 * 8]); \
        SET[mi][1] = *(const bf8_t*)(&As[BUF][aRd + (qm) * 4096 + mi * 1024 + g1 * 8]); } } while (0)
#define RD_B(SET, BUF, qn) do { _Pragma("unroll") \
    for (int ni = 0; ni < 2; ni++) { \
        SET[ni][0] = *(const bf8_t*)(&Bs[BUF][bRd + (qn) * 2048 + ni * 1024 + g0 * 8]); \
        SET[ni][1] = *(const bf8_t*)(&Bs[BUF][bRd + (qn) * 2048 + ni * 1024 + g1 * 8]); } } while (0)

    f4_t acc[8][4];
    #pragma unroll
    for (int mi = 0; mi < 8; mi++)
        #pragma unroll
        for (int ni = 0; ni < 4; ni++) {
            acc[mi][ni][0] = 0.f; acc[mi][ni][1] = 0.f;
            acc[mi][ni][2] = 0.f; acc[mi][ni][3] = 0.f;
        }

    bf8_t afX[4][2];   // A q0 (current tile), prefetched from nxt pre-C4
    bf8_t afY[4][2];   // A q1 (current tile), read intra-tile pre-C2
    bf8_t bV[2][2];    // B q1, read intra-tile pre-C1
    bf8_t bU0[2][2];   // B q0, even tiles
    bf8_t bU1[2][2];   // B q0, odd tiles (parity rotation kills the Q10 WAR)

#define MFMA_QUAD(AF, BF, QM, QN) do { \
    __builtin_amdgcn_s_setprio(1); \
    _Pragma("unroll") \
    for (int mi = 0; mi < 4; mi++) \
        _Pragma("unroll") \
        for (int ni = 0; ni < 2; ni++) { \
            acc[(QM)*4+mi][(QN)*2+ni] = __builtin_amdgcn_mfma_f32_16x16x32_bf16( \
                AF[mi][0], BF[ni][0], acc[(QM)*4+mi][(QN)*2+ni], 0, 0, 0); \
            acc[(QM)*4+mi][(QN)*2+ni] = __builtin_amdgcn_mfma_f32_16x16x32_bf16( \
                AF[mi][1], BF[ni][1], acc[(QM)*4+mi][(QN)*2+ni], 0, 0, 0); \
        } \
    __builtin_amdgcn_s_setprio(0); } while (0)

#define FENCE_LGKM() do { \
    asm volatile("s_waitcnt lgkmcnt(0)"); \
    __builtin_amdgcn_sched_barrier(0); } while (0)
#define SB0() __builtin_amdgcn_sched_barrier(0)

// One tile. Entry: 12 reads (afX q0 + BUSE q0 of this tile) outstanding, issued pre-C4
// of the previous tile. BUSE = this tile's B(q0) set; BNXT = next tile's (other parity).
#define TILE_BODY(TT, CUR, NXT, BUSE, BNXT) do { \
    if ((TT) < 15) STAGE_ALL(NXT, ((TT) + 1) * 64); \
    FENCE_LGKM();                    /* entry reads (drained under prev C4) */ \
    RD_B(bV, CUR, 1); SB0(); \
    MFMA_QUAD(afX, BUSE, 0, 0);      /* C1 Q00; bV drains underneath */ \
    FENCE_LGKM(); \
    RD_AF(afY, CUR, 1); SB0(); \
    MFMA_QUAD(afX, bV, 0, 1);        /* C2 Q01; afY drains underneath; afX dead */ \
    FENCE_LGKM(); \
    MFMA_QUAD(afY, bV, 1, 1);        /* C3 Q11; bV dead */ \
    if ((TT) < 15) { \
        asm volatile("s_waitcnt vmcnt(0)");   /* stages issued ~3 clusters ago */ \
        __builtin_amdgcn_s_barrier();         /* publish buf[NXT]; cur reads all fenced */ \
        RD_AF(afX, NXT, 0);                   /* afX last used C2 (gap C3) */ \
        RD_B(BNXT, NXT, 0); SB0();            /* BNXT idle since prev-parity tile */ \
    } \
    MFMA_QUAD(afY, BUSE, 1, 0);      /* C4 Q10; prefetch reads drain underneath */ \
} while (0)

    // ---- prologue: stage tile 0, publish, issue q00 frag reads ----
    STAGE_ALL(0, 0);
    asm volatile("s_waitcnt vmcnt(0)");
    __builtin_amdgcn_s_barrier();
    RD_AF(afX, 0, 0);
    RD_B(bU0, 0, 0);       // 12 outstanding -> entry invariant for tile 0

    // ---- main loop: 2-tile unroll keeps buffer indices and B-set parity compile-time ----
    for (int tt = 0; tt < 16; tt += 2) {
        TILE_BODY(tt,     0, 1, bU0, bU1);
        TILE_BODY(tt + 1, 1, 0, bU1, bU0);
    }

    // ---- C write: C/D layout col = lane&15, row = (lane>>4)*4 + reg [m89/m91 verified] ----
    #pragma unroll
    for (int mi = 0; mi < 8; mi++) {
        const int row = bm * 256 + wm * 128 + mi * 16 + quad * 4;
        #pragma unroll
        for (int ni = 0; ni < 4; ni++) {
            const int col = bn * 256 + wn * 64 + ni * 16 + l15;
            #pragma unroll
            for (int r = 0; r < 4; r++)
                C[(size_t)(row + r) * N_ROWS + col] = acc[mi][ni][r];
        }
    }

#undef STAGE_ALL
#undef RD_AF
#undef RD_B
#undef MFMA_QUAD
#undef FENCE_LGKM
#undef SB0
#undef TILE_BODY
}

extern "C" void kernel_launch(void* const* d_in, const int* in_sizes, int n_in,
                              void* d_out, int out_size, void* d_ws, size_t ws_size,
                              hipStream_t stream)
{
    const float* x = (const float*)d_in[0];
    const float* y = (const float*)d_in[1];
    float* out = (float*)d_out;

    unsigned short* xb = (unsigned short*)d_ws;                 // 8 MB
    unsigned short* yb = xb + (size_t)N_ROWS * D_K;             // 8 MB

    norm_rows_kernel<<<2 * N_ROWS, 256, 0, stream>>>(x, y, xb, yb);

    dim3 grid(N_ROWS / 256, N_ROWS / 256);                      // 16x16 = 256 blocks, 1/CU
    cosim_gemm256_kernel<<<grid, 512, 0, stream>>>(xb, yb, out);
}